// Round 2
// baseline (1565.412 us; speedup 1.0000x reference)
//
#include <hip/hip_runtime.h>
#include <math.h>

// B=4480, L=7, H=8, E=64, S=56, D=64, N_STATIONS=35
// out[b,l,h,d] = sum_s A[b,h,l,s] * ( P[n,l,s]*V[b,s,h,d] + (1-P[n,l,s])*0.1*Z[b,s,h,d] )
// A = softmax(QK^T/8) over s, n = b % 35, Z flat layout identical to V.
//
// One wave per (b,h). Register-lean, zero-LDS, zero-barrier design:
//  - lane (sl,c): sl=lane>>4 (s mod 4), c=lane&15 (float4 column of the 64-dim)
//  - Phase A streams K one float4/lane per iter; score(l, 4i+sl) reduced over c
//    by 4-step xor-butterfly, then *kept in the lane with c==i* -> after the
//    loop, lane (sl,c) owns score(l, s=4c+sl). No LDS round-trip.
//  - Softmax over s = full 64-lane butterfly on registers (8 dead lanes at -inf).
//  - Phase B: weight for s=4i+sl is pulled from lane (sl*16+i) via one __shfl.

namespace {
constexpr int kL = 7;
constexpr int kH = 8;
constexpr int kE = 64;
constexpr int kS = 56;
constexpr int kD = 64;
constexpr int kN = 35;
constexpr float kScale = 0.125f;     // 1/sqrt(64)
constexpr float kNoiseStd = 0.1f;
constexpr int kWaves = 4;            // one (b,h) pair per wave
}

typedef float f32x4 __attribute__((ext_vector_type(4)));

__global__ __launch_bounds__(256, 4)
void fullattn_fused_kernel(const float* __restrict__ Q,
                           const float* __restrict__ K,
                           const float* __restrict__ V,
                           const float* __restrict__ P,
                           const float* __restrict__ Z,
                           float* __restrict__ O)
{
    const int tid  = threadIdx.x;
    const int wid  = tid >> 6;
    const int lane = tid & 63;
    const int sl   = lane >> 4;   // 0..3
    const int c    = lane & 15;   // 0..15

    const int pair = blockIdx.x * kWaves + wid;   // (b,h)
    const int b = pair >> 3;
    const int h = pair & 7;
    const int n = b % kN;

    const float* qb = Q + ((size_t)b * kL * kH + h) * kE;
    const float* kb = K + ((size_t)b * kS * kH + h) * kE;
    const float* vb = V + ((size_t)b * kS * kH + h) * kD;
    const float* zb = Z + ((size_t)b * kS * kH + h) * kD;

    // ---- Q in registers: q4[l] = Q[b,l,h,4c..4c+3] (broadcast across sl groups)
    f32x4 q4[kL];
    #pragma unroll
    for (int l = 0; l < kL; ++l)
        q4[l] = *reinterpret_cast<const f32x4*>(qb + l * (kH * kE) + 4 * c);

    // ---- Phase A: stream K, distributed scores. x[l] ends as score(l, 4c+sl).
    float x[kL];
    #pragma unroll
    for (int l = 0; l < kL; ++l) x[l] = -INFINITY;

    #pragma unroll
    for (int i = 0; i < kS / 4; ++i) {
        const f32x4 k4 = *reinterpret_cast<const f32x4*>(
            kb + (4 * i + sl) * (kH * kE) + 4 * c);
        #pragma unroll
        for (int l = 0; l < kL; ++l) {
            float p = q4[l].x * k4.x + q4[l].y * k4.y
                    + q4[l].z * k4.z + q4[l].w * k4.w;
            p += __shfl_xor(p, 1);
            p += __shfl_xor(p, 2);
            p += __shfl_xor(p, 4);
            p += __shfl_xor(p, 8);
            if (c == i) x[l] = p;   // v_cndmask: lane (sl,i) keeps s=4i+sl
        }
    }

    // ---- Softmax over s (this lane's s = 4c+sl; lanes with c>=14 are dead)
    const int s_own = 4 * c + sl;
    const int s_idx = (s_own < kS) ? s_own : 0;        // clamp OOB P reads
    const float* prow = P + (size_t)n * kL * kS;

    float w1[kL], w2[kL];
    #pragma unroll
    for (int l = 0; l < kL; ++l) {
        const float xs = x[l] * kScale;                // -inf on dead lanes
        float m = xs;
        m = fmaxf(m, __shfl_xor(m, 1));
        m = fmaxf(m, __shfl_xor(m, 2));
        m = fmaxf(m, __shfl_xor(m, 4));
        m = fmaxf(m, __shfl_xor(m, 8));
        m = fmaxf(m, __shfl_xor(m, 16));
        m = fmaxf(m, __shfl_xor(m, 32));
        float e = __expf(xs - m);                      // 0 on dead lanes
        float sum = e;
        sum += __shfl_xor(sum, 1);
        sum += __shfl_xor(sum, 2);
        sum += __shfl_xor(sum, 4);
        sum += __shfl_xor(sum, 8);
        sum += __shfl_xor(sum, 16);
        sum += __shfl_xor(sum, 32);
        const float a = e / sum;
        float p = prow[l * kS + s_idx];
        p = fminf(fmaxf(p, 0.0f), 1.0f);
        w1[l] = a * p;
        w2[l] = a * (1.0f - p) * kNoiseStd;
    }

    // ---- Phase B: out[l][:] = sum_s w1*V[s] + w2*Z[s]; weight via one shfl
    f32x4 acc[kL];
    #pragma unroll
    for (int l = 0; l < kL; ++l) acc[l] = (f32x4)(0.0f);

    const int grp = lane & 48;    // sl*16
    #pragma unroll
    for (int i = 0; i < kS / 4; ++i) {
        const int s = 4 * i + sl;
        const f32x4 v4 = *reinterpret_cast<const f32x4*>(vb + s * (kH * kD) + 4 * c);
        const f32x4 z4 = *reinterpret_cast<const f32x4*>(zb + s * (kH * kD) + 4 * c);
        #pragma unroll
        for (int l = 0; l < kL; ++l) {
            const float ww1 = __shfl(w1[l], grp | i);
            const float ww2 = __shfl(w2[l], grp | i);
            acc[l] += ww1 * v4 + ww2 * z4;
        }
    }

    // ---- reduce the 4 sl groups, lanes of sl==0 store 256B per l
    #pragma unroll
    for (int l = 0; l < kL; ++l) {
        f32x4 a = acc[l];
        a.x += __shfl_xor(a.x, 16);
        a.y += __shfl_xor(a.y, 16);
        a.z += __shfl_xor(a.z, 16);
        a.w += __shfl_xor(a.w, 16);
        a.x += __shfl_xor(a.x, 32);
        a.y += __shfl_xor(a.y, 32);
        a.z += __shfl_xor(a.z, 32);
        a.w += __shfl_xor(a.w, 32);
        if (sl == 0) {
            __builtin_nontemporal_store(a, reinterpret_cast<f32x4*>(
                O + (((size_t)b * kL + l) * kH + h) * kD + 4 * c));
        }
    }
}

extern "C" void kernel_launch(void* const* d_in, const int* in_sizes, int n_in,
                              void* d_out, int out_size, void* d_ws, size_t ws_size,
                              hipStream_t stream) {
    const float* Q = (const float*)d_in[0];  // queries  [4480,7,8,64]
    const float* K = (const float*)d_in[1];  // keys     [4480,56,8,64]
    const float* V = (const float*)d_in[2];  // values   [4480,56,8,64]
    const float* P = (const float*)d_in[3];  // prob     [35,7,56]
    const float* Z = (const float*)d_in[4];  // noise    [128,35,56,8,64] == [4480,56,8,64]
    float* O = (float*)d_out;                // out      [4480,7,8,64]

    const int pairs = 4480 * 8;
    dim3 grid(pairs / kWaves);               // 8960 blocks x 256 threads
    fullattn_fused_kernel<<<grid, 256, 0, stream>>>(Q, K, V, P, Z, O);
}

// Round 3
// 579.356 us; speedup vs baseline: 2.7020x; 2.7020x over previous
//
#include <hip/hip_runtime.h>
#include <math.h>

// B=4480, L=7, H=8, E=64, S=56, D=64, N_STATIONS=35
// out[b,l,h,d] = sum_s A[b,h,l,s] * ( P[n,l,s]*V[b,s,h,d] + (1-P[n,l,s])*0.1*Z[b,s,h,d] )
// A = softmax(QK^T/8) over s, n = b % 35, Z flat layout identical to V.
//
// One wave per (b,h), 4 waves/block, no barriers (per-wave-private LDS).
// Phase A: lane s owns score row s. K row streamed one 64B line (4 f32x4) at a
//   time -> every fetched line fully consumed from registers; Q read via
//   lane-uniform broadcast loads (28 lines, L1-resident). Long-lived state is
//   just dot[7] -> no spill pressure.
// Softmax: direct (lane==s), 64-lane butterflies, dead lanes at -inf.
// Weights (w1,w2) written once to LDS as float2; Phase B reads them with
//   ds_read_b64 broadcasts while streaming V,Z coalesced in (sl,c) layout.

namespace {
constexpr int kL = 7;
constexpr int kH = 8;
constexpr int kE = 64;
constexpr int kS = 56;
constexpr int kD = 64;
constexpr int kN = 35;
constexpr float kScale = 0.125f;     // 1/sqrt(64)
constexpr float kNoiseStd = 0.1f;
constexpr int kWaves = 4;            // one (b,h) pair per wave
}

typedef float f32x4 __attribute__((ext_vector_type(4)));
typedef float f32x2 __attribute__((ext_vector_type(2)));

__global__ __launch_bounds__(256)
void fullattn_fused_kernel(const float* __restrict__ Q,
                           const float* __restrict__ K,
                           const float* __restrict__ V,
                           const float* __restrict__ P,
                           const float* __restrict__ Z,
                           float* __restrict__ O)
{
    __shared__ f32x2 sW[kWaves][kL * kS];   // per-wave private (w1,w2) pairs

    const int tid  = threadIdx.x;
    const int wid  = tid >> 6;
    const int lane = tid & 63;

    const int pair = blockIdx.x * kWaves + wid;   // (b,h)
    const int b = pair >> 3;
    const int h = pair & 7;
    const int n = b % kN;

    const float* qb = Q + ((size_t)b * kL * kH + h) * kE;
    const float* kb = K + ((size_t)b * kS * kH + h) * kE;
    const float* vb = V + ((size_t)b * kS * kH + h) * kD;
    const float* zb = Z + ((size_t)b * kS * kH + h) * kD;

    // ---------- Phase A: lane s owns score row s ----------
    const int s_idx = (lane < kS) ? lane : (kS - 1);    // clamp dead lanes
    const float* krow = kb + (size_t)s_idx * (kH * kE);

    float dot[kL];
    #pragma unroll
    for (int l = 0; l < kL; ++l) dot[l] = 0.0f;

    #pragma unroll
    for (int e16 = 0; e16 < 4; ++e16) {                 // one 64B K line / iter
        f32x4 k16[4];
        #pragma unroll
        for (int j = 0; j < 4; ++j)
            k16[j] = *reinterpret_cast<const f32x4*>(krow + 16 * e16 + 4 * j);
        #pragma unroll
        for (int j = 0; j < 4; ++j) {
            #pragma unroll
            for (int l = 0; l < kL; ++l) {
                const f32x4 q4 = *reinterpret_cast<const f32x4*>(
                    qb + l * (kH * kE) + 16 * e16 + 4 * j);   // lane-uniform
                dot[l] += q4.x * k16[j].x + q4.y * k16[j].y
                        + q4.z * k16[j].z + q4.w * k16[j].w;
            }
        }
    }

    // ---------- Softmax over s (lane==s), fold in P; write (w1,w2) to LDS ----
    const float* prow = P + (size_t)n * kL * kS;
    #pragma unroll
    for (int l = 0; l < kL; ++l) {
        const float xs = (lane < kS) ? dot[l] * kScale : -INFINITY;
        float m = xs;
        m = fmaxf(m, __shfl_xor(m, 1));
        m = fmaxf(m, __shfl_xor(m, 2));
        m = fmaxf(m, __shfl_xor(m, 4));
        m = fmaxf(m, __shfl_xor(m, 8));
        m = fmaxf(m, __shfl_xor(m, 16));
        m = fmaxf(m, __shfl_xor(m, 32));
        const float e = __expf(xs - m);                 // 0 on dead lanes
        float sum = e;
        sum += __shfl_xor(sum, 1);
        sum += __shfl_xor(sum, 2);
        sum += __shfl_xor(sum, 4);
        sum += __shfl_xor(sum, 8);
        sum += __shfl_xor(sum, 16);
        sum += __shfl_xor(sum, 32);
        const float a = e / sum;
        if (lane < kS) {
            float p = prow[l * kS + lane];
            p = fminf(fmaxf(p, 0.0f), 1.0f);
            f32x2 w;
            w.x = a * p;
            w.y = a * (1.0f - p) * kNoiseStd;
            sW[wid][l * kS + lane] = w;
        }
    }
    // wave-internal LDS write->read ordering handled by lgkmcnt; no barrier.

    // ---------- Phase B: (sl,c) layout, stream V,Z coalesced ----------
    const int sl = lane >> 4;     // 0..3
    const int c  = lane & 15;     // 0..15

    f32x4 acc[kL];
    #pragma unroll
    for (int l = 0; l < kL; ++l) acc[l] = (f32x4)(0.0f);

    #pragma unroll
    for (int i = 0; i < kS / 4; ++i) {
        const int s = 4 * i + sl;
        const f32x4 v4 = *reinterpret_cast<const f32x4*>(vb + s * (kH * kD) + 4 * c);
        const f32x4 z4 = *reinterpret_cast<const f32x4*>(zb + s * (kH * kD) + 4 * c);
        #pragma unroll
        for (int l = 0; l < kL; ++l) {
            const f32x2 w = sW[wid][l * kS + s];        // ds_read_b64 broadcast
            acc[l] += w.x * v4 + w.y * z4;
        }
    }

    // ---------- reduce sl groups, lanes of sl==0 store 256B per l ----------
    #pragma unroll
    for (int l = 0; l < kL; ++l) {
        f32x4 a = acc[l];
        a.x += __shfl_xor(a.x, 16);
        a.y += __shfl_xor(a.y, 16);
        a.z += __shfl_xor(a.z, 16);
        a.w += __shfl_xor(a.w, 16);
        a.x += __shfl_xor(a.x, 32);
        a.y += __shfl_xor(a.y, 32);
        a.z += __shfl_xor(a.z, 32);
        a.w += __shfl_xor(a.w, 32);
        if (sl == 0) {
            *reinterpret_cast<f32x4*>(
                O + (((size_t)b * kL + l) * kH + h) * kD + 4 * c) = a;
        }
    }
}

extern "C" void kernel_launch(void* const* d_in, const int* in_sizes, int n_in,
                              void* d_out, int out_size, void* d_ws, size_t ws_size,
                              hipStream_t stream) {
    const float* Q = (const float*)d_in[0];  // queries  [4480,7,8,64]
    const float* K = (const float*)d_in[1];  // keys     [4480,56,8,64]
    const float* V = (const float*)d_in[2];  // values   [4480,56,8,64]
    const float* P = (const float*)d_in[3];  // prob     [35,7,56]
    const float* Z = (const float*)d_in[4];  // noise    [128,35,56,8,64] == [4480,56,8,64]
    float* O = (float*)d_out;                // out      [4480,7,8,64]

    const int pairs = 4480 * 8;
    dim3 grid(pairs / kWaves);               // 8960 blocks x 256 threads
    fullattn_fused_kernel<<<grid, 256, 0, stream>>>(Q, K, V, P, Z, O);
}